// Round 1
// baseline (56.760 us; speedup 1.0000x reference)
//
#include <hip/hip_runtime.h>

#define S_LEN 64000
#define B_N   64
#define CHUNK 128
#define NCH   500   // 64000 / 128
#define KPL   8     // chunks per lane in scan kernel (64*8 = 512 >= 500)

// Per-step affine transform: state' = A*state + c, where A = 2H - I, c = 2*gHBx.
__device__ __forceinline__ void svf_step_coefs(float g, float R, float x,
    float& A00, float& A01, float& A10, float& A11, float& c0, float& c1)
{
    float T  = 1.0f / fmaf(g, g + R, 1.0f);   // 1/(1 + g*(g+2R))
    float gT = g * T;
    A00 = fmaf(2.0f, T, -1.0f);               // 2T - 1
    A01 = -2.0f * gT;
    A10 =  2.0f * gT;
    A11 = fmaf(2.0f, fmaf(R, gT, T), -1.0f);  // 2(R*g+1)*T - 1
    c0  = A10 * x;                            // 2*g*T*x
    c1  = g * c0;                             // 2*g^2*T*x
}

// Pass 1: per (chunk p, batch b) compose the chunk's affine transform.
// Lanes = batch -> loads are fully coalesced (256 B per step per array).
__global__ __launch_bounds__(64) void k_chunk(
    const float* __restrict__ audio, const float* __restrict__ g,
    const float* __restrict__ twoR, float* __restrict__ wsM)
{
    const int b = threadIdx.x;
    const int p = blockIdx.x;
    const int base = p * CHUNK * B_N + b;

    float M00 = 1.f, M01 = 0.f, M10 = 0.f, M11 = 1.f, v0 = 0.f, v1 = 0.f;

#pragma unroll 4
    for (int i = 0; i < CHUNK; ++i) {
        const int idx = base + i * B_N;
        float gg = g[idx], R = twoR[idx], x = audio[idx];
        float A00, A01, A10, A11, c0, c1;
        svf_step_coefs(gg, R, x, A00, A01, A10, A11, c0, c1);
        // acc = A ∘ acc
        float n00 = fmaf(A00, M00, A01 * M10);
        float n01 = fmaf(A00, M01, A01 * M11);
        float n10 = fmaf(A10, M00, A11 * M10);
        float n11 = fmaf(A10, M01, A11 * M11);
        float nv0 = fmaf(A00, v0, fmaf(A01, v1, c0));
        float nv1 = fmaf(A10, v0, fmaf(A11, v1, c1));
        M00 = n00; M01 = n01; M10 = n10; M11 = n11; v0 = nv0; v1 = nv1;
    }

    const int o = p * B_N + b;
    const int stride = NCH * B_N;
    wsM[o]              = M00;
    wsM[o + 1 * stride] = M01;
    wsM[o + 2 * stride] = M10;
    wsM[o + 3 * stride] = M11;
    wsM[o + 4 * stride] = v0;
    wsM[o + 5 * stride] = v1;
}

// Pass 2: one block per batch. Scan the NCH chunk transforms (affine compose)
// and emit each chunk's entry state. Lane-local compose of KPL chunks, then
// Hillis-Steele shuffle scan across 64 lanes.
__global__ __launch_bounds__(64) void k_scan(
    const float* __restrict__ wsM, float* __restrict__ sIn)
{
    const int b = blockIdx.x;   // batch
    const int l = threadIdx.x;  // lane
    const int stride = NCH * B_N;

    float cM[KPL][6];
#pragma unroll
    for (int k = 0; k < KPL; ++k) {
        const int p = l * KPL + k;
        if (p < NCH) {
            const int o = p * B_N + b;
            cM[k][0] = wsM[o];
            cM[k][1] = wsM[o + 1 * stride];
            cM[k][2] = wsM[o + 2 * stride];
            cM[k][3] = wsM[o + 3 * stride];
            cM[k][4] = wsM[o + 4 * stride];
            cM[k][5] = wsM[o + 5 * stride];
        } else {
            cM[k][0] = 1.f; cM[k][1] = 0.f; cM[k][2] = 0.f;
            cM[k][3] = 1.f; cM[k][4] = 0.f; cM[k][5] = 0.f;
        }
    }

    // lane-local inclusive compose (increasing chunk order): acc = T_p ∘ acc
    float M00 = 1.f, M01 = 0.f, M10 = 0.f, M11 = 1.f, v0 = 0.f, v1 = 0.f;
#pragma unroll
    for (int k = 0; k < KPL; ++k) {
        float A00 = cM[k][0], A01 = cM[k][1], A10 = cM[k][2],
              A11 = cM[k][3], c0 = cM[k][4], c1 = cM[k][5];
        float n00 = fmaf(A00, M00, A01 * M10);
        float n01 = fmaf(A00, M01, A01 * M11);
        float n10 = fmaf(A10, M00, A11 * M10);
        float n11 = fmaf(A10, M01, A11 * M11);
        float nv0 = fmaf(A00, v0, fmaf(A01, v1, c0));
        float nv1 = fmaf(A10, v0, fmaf(A11, v1, c1));
        M00 = n00; M01 = n01; M10 = n10; M11 = n11; v0 = nv0; v1 = nv1;
    }

    // inclusive wave scan: acc_l = L_l ∘ L_{l-1} ∘ ... ∘ L_0
#pragma unroll
    for (int d = 1; d < 64; d <<= 1) {
        float o00 = __shfl_up(M00, (unsigned)d, 64);
        float o01 = __shfl_up(M01, (unsigned)d, 64);
        float o10 = __shfl_up(M10, (unsigned)d, 64);
        float o11 = __shfl_up(M11, (unsigned)d, 64);
        float ov0 = __shfl_up(v0,  (unsigned)d, 64);
        float ov1 = __shfl_up(v1,  (unsigned)d, 64);
        if (l >= d) {
            // acc = acc ∘ other  (other covers earlier chunks)
            float n00 = fmaf(M00, o00, M01 * o10);
            float n01 = fmaf(M00, o01, M01 * o11);
            float n10 = fmaf(M10, o00, M11 * o10);
            float n11 = fmaf(M10, o01, M11 * o11);
            float nv0 = fmaf(M00, ov0, fmaf(M01, ov1, v0));
            float nv1 = fmaf(M10, ov0, fmaf(M11, ov1, v1));
            M00 = n00; M01 = n01; M10 = n10; M11 = n11; v0 = nv0; v1 = nv1;
        }
    }

    // exclusive prefix = inclusive of lane l-1; lane 0 = identity
    float E00 = __shfl_up(M00, 1u, 64);
    float E01 = __shfl_up(M01, 1u, 64);
    float E10 = __shfl_up(M10, 1u, 64);
    float E11 = __shfl_up(M11, 1u, 64);
    float Ev0 = __shfl_up(v0, 1u, 64);
    float Ev1 = __shfl_up(v1, 1u, 64);
    if (l == 0) { E00 = 1.f; E01 = 0.f; E10 = 0.f; E11 = 1.f; Ev0 = 0.f; Ev1 = 0.f; }

    // state at entry of chunk l*KPL: apply exclusive prefix to s0 = (1,1)
    float s0 = E00 + E01 + Ev0;
    float s1 = E10 + E11 + Ev1;

#pragma unroll
    for (int k = 0; k < KPL; ++k) {
        const int p = l * KPL + k;
        if (p < NCH) {
            sIn[(p * B_N + b) * 2]     = s0;
            sIn[(p * B_N + b) * 2 + 1] = s1;
            float ns0 = fmaf(cM[k][0], s0, fmaf(cM[k][1], s1, cM[k][4]));
            float ns1 = fmaf(cM[k][2], s0, fmaf(cM[k][3], s1, cM[k][5]));
            s0 = ns0; s1 = ns1;
        }
    }
}

// Pass 3: replay each chunk from its entry state, compute outputs, and
// transpose through padded LDS so [B,S] stores are coalesced.
__global__ __launch_bounds__(64) void k_out(
    const float* __restrict__ audio, const float* __restrict__ g,
    const float* __restrict__ twoR, const float* __restrict__ mix,
    const float* __restrict__ sIn, float* __restrict__ out)
{
    __shared__ float tile[64 * 65];
    const int b = threadIdx.x;
    const int p = blockIdx.x;

    float s0 = sIn[(p * B_N + b) * 2];
    float s1 = sIn[(p * B_N + b) * 2 + 1];

    for (int half = 0; half < CHUNK / 64; ++half) {
        const int tbase = p * CHUNK + half * 64;
#pragma unroll 4
        for (int i = 0; i < 64; ++i) {
            const int idx = (tbase + i) * B_N + b;
            float gg = g[idx], R = twoR[idx], x = audio[idx];
            float m0 = mix[idx * 3], m1 = mix[idx * 3 + 1], m2 = mix[idx * 3 + 2];

            float T  = 1.0f / fmaf(gg, gg + R, 1.0f);
            float gT = gg * T;
            float b0 = gT * x;
            float b1 = gg * b0;
            float Y0 = fmaf(T, s0, fmaf(-gT, s1, b0));
            float Y1 = fmaf(gT, s0, fmaf(fmaf(R, gT, T), s1, b1));
            s0 = fmaf(2.0f, Y0, -s0);
            s1 = fmaf(2.0f, Y1, -s1);

            float yh = x - fmaf(R, Y0, Y1);                    // y_hps
            float y  = fmaf(R * m0, Y0, fmaf(m1, Y1, m2 * yh)); // y_mixed

            tile[i * 65 + b] = y;   // [step][batch], pad 65 -> conflict-free
        }
        __syncthreads();
        // write out[batch r][tbase + lane], contiguous 256 B per instruction
#pragma unroll 8
        for (int r = 0; r < 64; ++r) {
            out[r * S_LEN + tbase + b] = tile[b * 65 + r];
        }
        __syncthreads();
    }
}

extern "C" void kernel_launch(void* const* d_in, const int* in_sizes, int n_in,
                              void* d_out, int out_size, void* d_ws, size_t ws_size,
                              hipStream_t stream)
{
    const float* audio = (const float*)d_in[0];
    const float* g     = (const float*)d_in[1];
    const float* twoR  = (const float*)d_in[2];
    const float* mix   = (const float*)d_in[3];
    float* out = (float*)d_out;

    float* wsM = (float*)d_ws;                    // 6 * NCH * 64 floats (768 KB)
    float* sIn = wsM + 6 * NCH * B_N;             // NCH * 64 * 2 floats (256 KB)

    k_chunk<<<dim3(NCH), dim3(64), 0, stream>>>(audio, g, twoR, wsM);
    k_scan <<<dim3(B_N), dim3(64), 0, stream>>>(wsM, sIn);
    k_out  <<<dim3(NCH), dim3(64), 0, stream>>>(audio, g, twoR, mix, sIn, out);
}

// Round 2
// 48.650 us; speedup vs baseline: 1.1667x; 1.1667x over previous
//
#include <hip/hip_runtime.h>

#define S_LEN 64000
#define B_N   64
#define CH    32          // steps per chunk (serial chain per wave)
#define NCH   2000        // S_LEN / CH
#define KPL   8           // chunks per thread in scan kernel
#define SCAN_T 256        // scan threads: SCAN_T*KPL = 2048 >= NCH

struct Aff { float m00, m01, m10, m11, v0, v1; };

__device__ __forceinline__ Aff aff_id() {
    Aff r; r.m00 = 1.f; r.m01 = 0.f; r.m10 = 0.f; r.m11 = 1.f; r.v0 = 0.f; r.v1 = 0.f;
    return r;
}

// X ∘ Y : apply Y first, then X
__device__ __forceinline__ Aff aff_comp(const Aff& X, const Aff& Y) {
    Aff r;
    r.m00 = fmaf(X.m00, Y.m00, X.m01 * Y.m10);
    r.m01 = fmaf(X.m00, Y.m01, X.m01 * Y.m11);
    r.m10 = fmaf(X.m10, Y.m00, X.m11 * Y.m10);
    r.m11 = fmaf(X.m10, Y.m01, X.m11 * Y.m11);
    r.v0  = fmaf(X.m00, Y.v0, fmaf(X.m01, Y.v1, X.v0));
    r.v1  = fmaf(X.m10, Y.v0, fmaf(X.m11, Y.v1, X.v1));
    return r;
}

// Per-step transform: state' = A*state + c, A = 2H - I, c = 2*gHBx
__device__ __forceinline__ Aff svf_step(float g, float R, float x) {
    Aff a;
    float T  = 1.0f / fmaf(g, g + R, 1.0f);
    float gT = g * T;
    a.m00 = fmaf(2.0f, T, -1.0f);
    a.m01 = -2.0f * gT;
    a.m10 =  2.0f * gT;
    a.m11 = fmaf(2.0f, fmaf(R, gT, T), -1.0f);
    a.v0  = a.m10 * x;
    a.v1  = g * a.v0;
    return a;
}

// Pass 1: 4 waves/block, wave w composes chunk p = bid*4+w (32 steps).
// Lane = batch -> 256 B coalesced loads per step per array.
__global__ __launch_bounds__(256) void k_chunk(
    const float* __restrict__ audio, const float* __restrict__ g,
    const float* __restrict__ twoR, float* __restrict__ wsM)
{
    const int b = threadIdx.x & 63;
    const int w = threadIdx.x >> 6;
    const int p = blockIdx.x * 4 + w;
    const int base = p * CH * B_N + b;

    Aff acc = aff_id();
#pragma unroll 8
    for (int i = 0; i < CH; ++i) {
        const int idx = base + i * B_N;
        Aff a = svf_step(g[idx], twoR[idx], audio[idx]);
        acc = aff_comp(a, acc);
    }

    const int o = p * B_N + b;
    const int stride = NCH * B_N;
    wsM[o]              = acc.m00;
    wsM[o + 1 * stride] = acc.m01;
    wsM[o + 2 * stride] = acc.m10;
    wsM[o + 3 * stride] = acc.m11;
    wsM[o + 4 * stride] = acc.v0;
    wsM[o + 5 * stride] = acc.v1;
}

// Pass 2: one block (256 threads) per batch. Thread t owns chunks
// [t*KPL, t*KPL+KPL). Lane-local compose -> wave shuffle scan -> LDS
// cross-wave combine -> emit per-chunk entry states.
__global__ __launch_bounds__(SCAN_T) void k_scan(
    const float* __restrict__ wsM, float* __restrict__ sIn)
{
    const int b = blockIdx.x;
    const int t = threadIdx.x;
    const int lane = t & 63;
    const int wave = t >> 6;
    const int stride = NCH * B_N;

    Aff cM[KPL];
#pragma unroll
    for (int k = 0; k < KPL; ++k) {
        const int p = t * KPL + k;
        if (p < NCH) {
            const int o = p * B_N + b;
            cM[k].m00 = wsM[o];
            cM[k].m01 = wsM[o + 1 * stride];
            cM[k].m10 = wsM[o + 2 * stride];
            cM[k].m11 = wsM[o + 3 * stride];
            cM[k].v0  = wsM[o + 4 * stride];
            cM[k].v1  = wsM[o + 5 * stride];
        } else {
            cM[k] = aff_id();
        }
    }

    // thread-local inclusive compose (increasing chunk order)
    Aff acc = aff_id();
#pragma unroll
    for (int k = 0; k < KPL; ++k) acc = aff_comp(cM[k], acc);

    // wave-inclusive Hillis-Steele scan
#pragma unroll
    for (int d = 1; d < 64; d <<= 1) {
        Aff o;
        o.m00 = __shfl_up(acc.m00, (unsigned)d, 64);
        o.m01 = __shfl_up(acc.m01, (unsigned)d, 64);
        o.m10 = __shfl_up(acc.m10, (unsigned)d, 64);
        o.m11 = __shfl_up(acc.m11, (unsigned)d, 64);
        o.v0  = __shfl_up(acc.v0,  (unsigned)d, 64);
        o.v1  = __shfl_up(acc.v1,  (unsigned)d, 64);
        if (lane >= d) acc = aff_comp(acc, o);
    }

    // wave totals -> LDS
    __shared__ Aff wt[SCAN_T / 64];
    if (lane == 63) wt[wave] = acc;
    __syncthreads();

    // exclusive within wave
    Aff E;
    E.m00 = __shfl_up(acc.m00, 1u, 64);
    E.m01 = __shfl_up(acc.m01, 1u, 64);
    E.m10 = __shfl_up(acc.m10, 1u, 64);
    E.m11 = __shfl_up(acc.m11, 1u, 64);
    E.v0  = __shfl_up(acc.v0,  1u, 64);
    E.v1  = __shfl_up(acc.v1,  1u, 64);
    if (lane == 0) E = aff_id();

    // compose earlier waves' totals (chunk order: wave 0 first)
    Aff P = aff_id();
    for (int j = 0; j < wave; ++j) P = aff_comp(wt[j], P);
    E = aff_comp(E, P);

    // entry state of chunk t*KPL: apply E to s0 = (1,1)
    float s0 = E.m00 + E.m01 + E.v0;
    float s1 = E.m10 + E.m11 + E.v1;

#pragma unroll
    for (int k = 0; k < KPL; ++k) {
        const int p = t * KPL + k;
        if (p < NCH) {
            sIn[(p * B_N + b) * 2]     = s0;
            sIn[(p * B_N + b) * 2 + 1] = s1;
            float n0 = fmaf(cM[k].m00, s0, fmaf(cM[k].m01, s1, cM[k].v0));
            float n1 = fmaf(cM[k].m10, s0, fmaf(cM[k].m11, s1, cM[k].v1));
            s0 = n0; s1 = n1;
        }
    }
}

// Pass 3: 4 waves/block, wave w replays chunk p = bid*4+w from its entry
// state; block covers 128 consecutive steps; transpose via padded LDS so
// [B,S] stores are 256 B coalesced.
__global__ __launch_bounds__(256) void k_out(
    const float* __restrict__ audio, const float* __restrict__ g,
    const float* __restrict__ twoR, const float* __restrict__ mix,
    const float* __restrict__ sIn, float* __restrict__ out)
{
    __shared__ float tile[128 * 65];
    const int b = threadIdx.x & 63;
    const int w = threadIdx.x >> 6;
    const int p = blockIdx.x * 4 + w;
    const int tbase = p * CH;

    float s0 = sIn[(p * B_N + b) * 2];
    float s1 = sIn[(p * B_N + b) * 2 + 1];

#pragma unroll 4
    for (int i = 0; i < CH; ++i) {
        const int idx = (tbase + i) * B_N + b;
        float gg = g[idx], R = twoR[idx], x = audio[idx];
        float m0 = mix[idx * 3], m1 = mix[idx * 3 + 1], m2 = mix[idx * 3 + 2];

        float T  = 1.0f / fmaf(gg, gg + R, 1.0f);
        float gT = gg * T;
        float b0 = gT * x;
        float b1 = gg * b0;
        float Y0 = fmaf(T, s0, fmaf(-gT, s1, b0));
        float Y1 = fmaf(gT, s0, fmaf(fmaf(R, gT, T), s1, b1));
        s0 = fmaf(2.0f, Y0, -s0);
        s1 = fmaf(2.0f, Y1, -s1);

        float yh = x - fmaf(R, Y0, Y1);
        float y  = fmaf(R * m0, Y0, fmaf(m1, Y1, m2 * yh));

        tile[(w * CH + i) * 65 + b] = y;
    }
    __syncthreads();

    // block writes out[r][colbase .. colbase+127]; 64-lane groups write
    // 256 B contiguous; LDS reads are 2-way conflict max (free).
    const int col = threadIdx.x & 127;
    const int r0  = threadIdx.x >> 7;
    const int colbase = blockIdx.x * 128;
#pragma unroll
    for (int r = r0; r < 64; r += 2) {
        out[r * S_LEN + colbase + col] = tile[col * 65 + r];
    }
}

extern "C" void kernel_launch(void* const* d_in, const int* in_sizes, int n_in,
                              void* d_out, int out_size, void* d_ws, size_t ws_size,
                              hipStream_t stream)
{
    const float* audio = (const float*)d_in[0];
    const float* g     = (const float*)d_in[1];
    const float* twoR  = (const float*)d_in[2];
    const float* mix   = (const float*)d_in[3];
    float* out = (float*)d_out;

    float* wsM = (float*)d_ws;            // 6 * NCH * 64 floats (~3.1 MB)
    float* sIn = wsM + 6 * NCH * B_N;     // NCH * 64 * 2 floats (~1.0 MB)

    k_chunk<<<dim3(NCH / 4), dim3(256), 0, stream>>>(audio, g, twoR, wsM);
    k_scan <<<dim3(B_N), dim3(SCAN_T), 0, stream>>>(wsM, sIn);
    k_out  <<<dim3(NCH / 4), dim3(256), 0, stream>>>(audio, g, twoR, mix, sIn, out);
}